// Round 7
// baseline (108.084 us; speedup 1.0000x reference)
//
#include <hip/hip_runtime.h>
#include <math.h>

// ---------------------------------------------------------------------------
// QCNN_Diff R7: R6 algorithm (validated absmax 0.0) + occupancy repair.
//  - __launch_bounds__(256) WITHOUT min-waves: R6's (256,8) forced a 64-VGPR
//    cap below the rx-head's natural ~70 live regs -> scratch spills (theory
//    for R5/R6 flatness). Let the allocator land 56-72 organically.
//  - rz head: ph[16] array (16 VGPRs) replaced by inline per-slot phase
//    recompute (aa + masked kk adds, 5 regs live).
//  - per-head sincos recompute kept (16 regs not persisted across branches).
//  - wave-uniform gate data still enters VOP3P via SGPR operands ("s").
// slot bits: q3->S0 q7->S1 q5->S2 q1->S3; lane bits: q0->L0 q2->L1 q4->L2 q6->L3
// ---------------------------------------------------------------------------

typedef float v2f __attribute__((ext_vector_type(2)));

__device__ __forceinline__ v2f mk2(float a, float b) { v2f r; r.x = a; r.y = b; return r; }
__device__ __forceinline__ v2f ld2(const float* __restrict__ p) { return *(const v2f*)p; }

// ---- VOP3P primitives, VGPR x VGPR (for data*data complex mul) -------------
__device__ __forceinline__ v2f pk_mul_s(v2f a, v2f b) { v2f d;
  asm("v_pk_mul_f32 %0, %1, %2 op_sel:[0,0] op_sel_hi:[0,1]" : "=v"(d) : "v"(a), "v"(b)); return d; }
__device__ __forceinline__ v2f pk_fma_irot(v2f a, v2f b, v2f c) { v2f d;
  asm("v_pk_fma_f32 %0, %1, %2, %3 op_sel:[1,1,0] op_sel_hi:[1,0,1] neg_lo:[0,1,0]" : "=v"(d) : "v"(a), "v"(b), "v"(c)); return d; }
__device__ __forceinline__ v2f cmul(v2f a, v2f b) { return pk_fma_irot(a, b, pk_mul_s(a, b)); }
// d = (a.hi*b.lo, a.lo*b.hi)  (measurement Im(a*conj(b)) helper)
__device__ __forceinline__ v2f pk_mul_swap(v2f a, v2f b) { v2f d;
  asm("v_pk_mul_f32 %0, %1, %2 op_sel:[1,0] op_sel_hi:[0,1]" : "=v"(d) : "v"(a), "v"(b)); return d; }

// ---- VOP3P primitives, SGPR (wave-uniform) first operand -------------------
__device__ __forceinline__ v2f pk_mul_sM(v2f M, v2f b) { v2f d;
  asm("v_pk_mul_f32 %0, %1, %2 op_sel:[0,0] op_sel_hi:[0,1]" : "=v"(d) : "s"(M), "v"(b)); return d; }
__device__ __forceinline__ v2f pk_fma_sloM(v2f M, v2f b, v2f c) { v2f d;
  asm("v_pk_fma_f32 %0, %1, %2, %3 op_sel:[0,0,0] op_sel_hi:[0,1,1]" : "=v"(d) : "s"(M), "v"(b), "v"(c)); return d; }
__device__ __forceinline__ v2f pk_fma_shiM(v2f M, v2f b, v2f c) { v2f d;
  asm("v_pk_fma_f32 %0, %1, %2, %3 op_sel:[1,0,0] op_sel_hi:[1,1,1]" : "=v"(d) : "s"(M), "v"(b), "v"(c)); return d; }
__device__ __forceinline__ v2f pk_fma_shi_negM(v2f M, v2f b, v2f c) { v2f d;
  asm("v_pk_fma_f32 %0, %1, %2, %3 op_sel:[1,0,0] op_sel_hi:[1,1,1] neg_lo:[1,0,0] neg_hi:[1,0,0]" : "=v"(d) : "s"(M), "v"(b), "v"(c)); return d; }
__device__ __forceinline__ v2f pk_fma_rotM(v2f M, v2f b, v2f c) { v2f d;
  asm("v_pk_fma_f32 %0, %1, %2, %3 op_sel:[1,1,0] op_sel_hi:[1,0,1] neg_hi:[0,1,0]" : "=v"(d) : "s"(M), "v"(b), "v"(c)); return d; }
__device__ __forceinline__ v2f pk_fma_irotM(v2f M, v2f b, v2f c) { v2f d;
  asm("v_pk_fma_f32 %0, %1, %2, %3 op_sel:[1,1,0] op_sel_hi:[1,0,1] neg_lo:[0,1,0]" : "=v"(d) : "s"(M), "v"(b), "v"(c)); return d; }

template <int MASK>
__device__ __forceinline__ float swz1(float v) {
  constexpr int pat = (MASK << 10) | 0x1F;  // xor-mode
  return __int_as_float(__builtin_amdgcn_ds_swizzle(__float_as_int(v), pat));
}
template <int MASK>
__device__ __forceinline__ v2f swz2(v2f v) {
  v2f r; r.x = swz1<MASK>(v.x); r.y = swz1<MASK>(v.y); return r;
}

// ---- u3 row: ua*a + ub*b, matrices from SGPRs ------------------------------
template <bool A_REAL>
__device__ __forceinline__ v2f u3row_s(v2f ua, v2f ub, v2f a, v2f b) {
  v2f t = pk_mul_sM(ua, a);
  if constexpr (!A_REAL) t = pk_fma_irotM(ua, a, t);
  t = pk_fma_sloM(ub, b, t);
  return pk_fma_irotM(ub, b, t);
}

template <int SB>
__device__ __forceinline__ void u3_apply(v2f w[16], const float* __restrict__ p) {
  const v2f M0 = ld2(p), M1 = ld2(p + 2), M2 = ld2(p + 4), M3 = ld2(p + 6);
#pragma unroll
  for (int s0 = 0; s0 < 16; ++s0) {
    if (s0 & (1 << SB)) continue;
    const int s1 = s0 | (1 << SB);
    const v2f a = w[s0], b = w[s1];
    w[s0] = u3row_s<true>(M0, M1, a, b);
    w[s1] = u3row_s<false>(M3, M2, b, a);
  }
}

template <int SB, int CB, bool M00R>
__device__ __forceinline__ void u3_sel(v2f w[16], const float* __restrict__ pM,
                                       const float* __restrict__ pN) {
  const v2f M0 = ld2(pM), M1 = ld2(pM + 2), M2 = ld2(pM + 4), M3 = ld2(pM + 6);
  const v2f N0 = ld2(pN), N1 = ld2(pN + 2), N2 = ld2(pN + 4), N3 = ld2(pN + 6);
#pragma unroll
  for (int s0 = 0; s0 < 16; ++s0) {
    if (s0 & (1 << SB)) continue;
    const int s1 = s0 | (1 << SB);
    const v2f a = w[s0], b = w[s1];
    if ((s0 >> CB) & 1) {
      w[s0] = u3row_s<false>(N0, N1, a, b);
      w[s1] = u3row_s<false>(N3, N2, b, a);
    } else {
      w[s0] = u3row_s<M00R>(M0, M1, a, b);
      w[s1] = u3row_s<false>(M3, M2, b, a);
    }
  }
}

// ---- rx CR, ctrl slot SB, tgt lane LB (coefficients uniform for rx) --------
template <int SB, int LB>
__device__ __forceinline__ void crx_Sc_Lt(v2f w[16], v2f cs) {
#pragma unroll
  for (int s = 0; s < 16; ++s) {
    if (!(s & (1 << SB))) continue;
    const v2f p = swz2<(1 << LB)>(w[s]);
    w[s] = pk_fma_rotM(cs, p, pk_mul_sM(cs, w[s]));
  }
}

// ---- ry CR on REAL state, ctrl slot SB, tgt lane LB ------------------------
template <int SB, int LB>
__device__ __forceinline__ void cr_ry_r(float w[16], v2f cs, int gl) {
  const bool tb = (gl >> LB) & 1;
  const float Ky = tb ? cs.y : -cs.y;
#pragma unroll
  for (int s = 0; s < 16; ++s) {
    if (!(s & (1 << SB))) continue;
    const float p = swz1<(1 << LB)>(w[s]);
    w[s] = __builtin_fmaf(Ky, p, cs.x * w[s]);
  }
}

// ---- CR ctrl slot SBc, tgt slot SBt ----------------------------------------
template <int KIND, int SBc, int SBt>
__device__ __forceinline__ void cr_Sc_St(v2f w[16], v2f cs) {
#pragma unroll
  for (int s0 = 0; s0 < 16; ++s0) {
    if (!(s0 & (1 << SBc))) continue;
    if constexpr (KIND == 2) {
      const v2f t = pk_mul_sM(cs, w[s0]);
      w[s0] = (s0 & (1 << SBt)) ? pk_fma_irotM(cs, w[s0], t)
                                : pk_fma_rotM(cs, w[s0], t);
    } else {
      if (s0 & (1 << SBt)) continue;
      const int s1 = s0 | (1 << SBt);
      const v2f a = w[s0], b = w[s1];
      if constexpr (KIND == 0) {
        w[s0] = pk_fma_rotM(cs, b, pk_mul_sM(cs, a));
        w[s1] = pk_fma_rotM(cs, a, pk_mul_sM(cs, b));
      } else {
        w[s0] = pk_fma_shi_negM(cs, b, pk_mul_sM(cs, a));
        w[s1] = pk_fma_shiM(cs, a, pk_mul_sM(cs, b));
      }
    }
  }
}

// ---- lift real state through u3 on slot bit SB -----------------------------
template <int SB>
__device__ __forceinline__ void u3_lift(v2f w[16], const float wr[16],
                                        const float* __restrict__ p) {
  const v2f M0 = ld2(p), M1 = ld2(p + 2), M2 = ld2(p + 4), M3 = ld2(p + 6);
#pragma unroll
  for (int s0 = 0; s0 < 16; ++s0) {
    if (s0 & (1 << SB)) continue;
    const int s1 = s0 | (1 << SB);
    const float a = wr[s0], b = wr[s1];
    w[s0] = mk2(__builtin_fmaf(a, M0.x, b * M1.x), b * M1.y);  // u00 imag==0
    w[s1] = mk2(__builtin_fmaf(a, M2.x, b * M3.x),
                __builtin_fmaf(a, M2.y, b * M3.y));
  }
}

// ---- measurement: final U3(3) folded into quadratic form -------------------
__device__ __forceinline__ v2f measure(v2f w[16], const float* __restrict__ q) {
  const v2f qa = ld2(q);      // (alpha, beta)
  const v2f qg = ld2(q + 2);  // (gr, gi)
  float z3a = 0.f, z3b = 0.f, z7p = 0.f, z7m = 0.f;
#pragma unroll
  for (int s0 = 0; s0 < 16; s0 += 2) {
    const v2f a = w[s0], b = w[s0 + 1];
    const v2f t1 = a * b, t2 = pk_mul_swap(a, b), t3 = a * a, t4 = b * b;
    const float r = t1.x + t1.y;
    const float m = t2.x - t2.y;
    const float na = t3.x + t3.y;
    const float nb = t4.x + t4.y;
    z3a = __builtin_fmaf(qa.x, na, z3a);
    z3b = __builtin_fmaf(qa.y, nb, z3b);
    z3a = __builtin_fmaf(qg.x, r, z3a);
    z3b = __builtin_fmaf(-qg.y, m, z3b);
    const float nn = na + nb;
    if (s0 & 2) z7m += nn; else z7p += nn;
  }
  float z3 = z3a + z3b, z7 = z7p - z7m;
  z3 += swz1<1>(z3); z7 += swz1<1>(z7);
  z3 += swz1<2>(z3); z7 += swz1<2>(z7);
  z3 += swz1<4>(z3); z7 += swz1<4>(z7);
  z3 += swz1<8>(z3); z7 += swz1<8>(z7);
  return mk2(z3, z7);
}

template <int KIND>
__device__ __forceinline__ v2f tail_common(v2f w[16], const float* __restrict__ Gb) {
  u3_sel<0, 3, true>(w, Gb + 72, Gb + 80);    // U3first(3) / R13.U3first(3)
  u3_apply<2>(w, Gb + 88);                    // U3(5)
  u3_sel<1, 2, false>(w, Gb + 96, Gb + 104);  // Uf7.U7 / Uf7.R57.U7
  cr_Sc_St<KIND, 0, 2>(w, ld2(Gb + 56));      // CR(3,5)
  return measure(w, Gb + 112);                // folds U3final(3)
}

__device__ __forceinline__ void load_sincos(const float* __restrict__ xb,
                                            float sn[8], float cn[8]) {
  const float4 xlo = ((const float4*)xb)[0];
  const float4 xhi = ((const float4*)xb)[1];
  const float xq[8] = {xlo.x, xlo.y, xlo.z, xlo.w, xhi.x, xhi.y, xhi.z, xhi.w};
#pragma unroll
  for (int q = 0; q < 8; ++q) __sincosf(0.5f * xq[q], &sn[q], &cn[q]);
}

// ============================ branch heads ==================================
__device__ __forceinline__ v2f run_rx(const float* __restrict__ xb,
                                      const float* __restrict__ Gb, int gl) {
  float sn[8], cn[8];
  load_sincos(xb, sn, cn);
  const bool l0 = gl & 1, l1 = (gl >> 1) & 1, l2 = (gl >> 2) & 1, l3 = (gl >> 3) & 1;
  v2f pa[4], pb[4];
#pragma unroll
  for (int pr = 0; pr < 4; ++pr) {
    const bool lh = (pr == 0) ? l0 : (pr == 1) ? l1 : (pr == 2) ? l2 : l3;
    const float c = Gb[pr * 8], s = Gb[pr * 8 + 1];
    const float uc = lh ? sn[2 * pr] : cn[2 * pr];
    const float b0 = uc * cn[2 * pr + 1], b1 = uc * sn[2 * pr + 1];
    const float Kx = lh ? c : 1.f;
    const float Kyn = lh ? -s : 0.f;
    pa[pr] = mk2(Kx * b0, Kyn * b1);
    pb[pr] = mk2(Kx * b1, Kyn * b0);
  }
  v2f A[4] = {cmul(pa[0], pa[2]), cmul(pa[0], pb[2]), cmul(pb[0], pa[2]), cmul(pb[0], pb[2])};
  v2f Bv[4] = {cmul(pa[3], pa[1]), cmul(pa[3], pb[1]), cmul(pb[3], pa[1]), cmul(pb[3], pb[1])};
  v2f w[16];
#pragma unroll
  for (int s = 0; s < 16; ++s) w[s] = cmul(A[s >> 2], Bv[s & 3]);
  crx_Sc_Lt<3, 1>(w, ld2(Gb + 32));  // (1,2)
  crx_Sc_Lt<0, 2>(w, ld2(Gb + 40));  // (3,4)
  crx_Sc_Lt<2, 3>(w, ld2(Gb + 48));  // (5,6)
  u3_apply<3>(w, Gb + 64);           // U3(1)
  return tail_common<0>(w, Gb);
}

__device__ __forceinline__ v2f run_ry(const float* __restrict__ xb,
                                      const float* __restrict__ Gb, int gl) {
  float sn[8], cn[8];
  load_sincos(xb, sn, cn);
  const bool l0 = gl & 1, l1 = (gl >> 1) & 1, l2 = (gl >> 2) & 1, l3 = (gl >> 3) & 1;
  float pa[4], pb[4];
#pragma unroll
  for (int pr = 0; pr < 4; ++pr) {
    const bool lh = (pr == 0) ? l0 : (pr == 1) ? l1 : (pr == 2) ? l2 : l3;
    const float c = Gb[pr * 8], s = Gb[pr * 8 + 1];
    const float uc = lh ? sn[2 * pr] : cn[2 * pr];
    const float b0 = uc * cn[2 * pr + 1], b1 = uc * sn[2 * pr + 1];
    const float Kx = lh ? c : 1.f;
    const float Ky = lh ? s : 0.f;
    pa[pr] = Kx * b0 - Ky * b1;
    pb[pr] = Ky * b0 + Kx * b1;
  }
  const float A[4] = {pa[0] * pa[2], pa[0] * pb[2], pb[0] * pa[2], pb[0] * pb[2]};
  const float Bv[4] = {pa[3] * pa[1], pa[3] * pb[1], pb[3] * pa[1], pb[3] * pb[1]};
  float wr[16];
#pragma unroll
  for (int s = 0; s < 16; ++s) wr[s] = A[s >> 2] * Bv[s & 3];
  cr_ry_r<3, 1>(wr, ld2(Gb + 32), gl);
  cr_ry_r<0, 2>(wr, ld2(Gb + 40), gl);
  cr_ry_r<2, 3>(wr, ld2(Gb + 48), gl);
  v2f w[16];
  u3_lift<3>(w, wr, Gb + 64);        // U3(1), real input
  return tail_common<1>(w, Gb);
}

__device__ __forceinline__ v2f run_rz(const float* __restrict__ xb,
                                      const float* __restrict__ Gb, int gl) {
  float sn[8], cn[8];
  load_sincos(xb, sn, cn);
  const bool l0 = gl & 1, l1 = (gl >> 1) & 1, l2 = (gl >> 2) & 1, l3 = (gl >> 3) & 1;
  // real product state (encode)
  const float u0 = l0 ? sn[0] : cn[0];
  const float u2 = l1 ? sn[2] : cn[2];
  const float u4 = l2 ? sn[4] : cn[4];
  const float u6 = l3 ? sn[6] : cn[6];
  const float P = (u0 * u2) * (u4 * u6);
  float v01[4], v23[4];  // v01[(s1<<1)|s0] = P*A3[s0]*A7[s1]; v23[(s3<<1)|s2] = A5[s2]*A1[s3]
  v01[0] = P * (cn[3] * cn[7]); v01[1] = P * (sn[3] * cn[7]);
  v01[2] = P * (cn[3] * sn[7]); v01[3] = P * (sn[3] * sn[7]);
  v23[0] = cn[5] * cn[1]; v23[1] = sn[5] * cn[1];
  v23[2] = cn[5] * sn[1]; v23[3] = sn[5] * sn[1];
  // 7 CRZ gates as linear phase form: phi(s) = aa + sum_b s_b * k_b
  const float t0 = Gb[2], h0 = Gb[3];
  const float t1 = Gb[10], h1 = Gb[11];
  const float t2 = Gb[18], h2 = Gb[19];
  const float t3 = Gb[26], h3 = Gb[27];
  const float h4 = Gb[35], h5 = Gb[43], h6 = Gb[51];
  const float kk0 = (l1 ? t1 : 0.f) + (l2 ? h5 : -h5);   // S0=q3
  const float kk1 = (l3 ? t3 : 0.f);                      // S1=q7
  const float kk2 = (l2 ? t2 : 0.f) + (l3 ? h6 : -h6);   // S2=q5
  const float kk3 = (l0 ? t0 : 0.f) + (l1 ? h4 : -h4);   // S3=q1
  const float aa = -((l0 ? h0 : 0.f) + (l1 ? h1 : 0.f) + (l2 ? h2 : 0.f) + (l3 ? h3 : 0.f));
  v2f w[16];
#pragma unroll
  for (int s = 0; s < 16; ++s) {
    float phv = aa;
    if (s & 1) phv += kk0;
    if (s & 2) phv += kk1;
    if (s & 4) phv += kk2;
    if (s & 8) phv += kk3;
    float sp, cp;
    __sincosf(phv, &sp, &cp);
    const float e = v01[s & 3] * v23[s >> 2];
    w[s] = mk2(e * cp, e * sp);
  }
  u3_apply<3>(w, Gb + 64);           // U3(1)
  return tail_common<2>(w, Gb);
}

// ============================ prep ==========================================
struct c2 { float r, i; };
__device__ __forceinline__ c2 cmulh(c2 a, c2 b) { return {a.r * b.r - a.i * b.i, a.r * b.i + a.i * b.r}; }
__device__ __forceinline__ c2 cmulc(c2 a, c2 b) { return {a.r * b.r + a.i * b.i, a.i * b.r - a.r * b.i}; }  // a*conj(b)
__device__ __forceinline__ c2 caddh(c2 a, c2 b) { return {a.r + b.r, a.i + b.i}; }
__device__ void mat2mul(const c2 A[4], const c2 B[4], c2 C[4]) {
  C[0] = caddh(cmulh(A[0], B[0]), cmulh(A[1], B[2]));
  C[1] = caddh(cmulh(A[0], B[1]), cmulh(A[1], B[3]));
  C[2] = caddh(cmulh(A[2], B[0]), cmulh(A[3], B[2]));
  C[3] = caddh(cmulh(A[2], B[1]), cmulh(A[3], B[3]));
}
__device__ void u3m(const float* p, c2 M[4]) {
  float st, ct, sp, cp, sl, cl;
  sincosf(0.5f * p[0], &st, &ct);
  sincosf(p[1], &sp, &cp);
  sincosf(p[2], &sl, &cl);
  M[0] = {ct, 0.f};
  M[1] = {-cl * st, -sl * st};
  M[2] = {cp * st, sp * st};
  M[3] = {(cp * cl - sp * sl) * ct, (sp * cl + cp * sl) * ct};
}
__device__ void rmat(int kind, float th, c2 R[4]) {
  float s, c;
  sincosf(0.5f * th, &s, &c);
  if (kind == 0) { R[0] = {c, 0.f}; R[1] = {0.f, -s}; R[2] = {0.f, -s}; R[3] = {c, 0.f}; }
  else if (kind == 1) { R[0] = {c, 0.f}; R[1] = {-s, 0.f}; R[2] = {s, 0.f}; R[3] = {c, 0.f}; }
  else { R[0] = {c, -s}; R[1] = {0.f, 0.f}; R[2] = {0.f, 0.f}; R[3] = {c, s}; }
}
__device__ void storeM(float* dst, const c2 M[4]) {
#pragma unroll
  for (int j = 0; j < 4; ++j) { dst[2 * j] = M[j].r; dst[2 * j + 1] = M[j].i; }
}

__global__ void qcnn_prep(const float* __restrict__ crx, const float* __restrict__ u3x,
                          const float* __restrict__ cry, const float* __restrict__ u3y,
                          const float* __restrict__ crz, const float* __restrict__ u3z,
                          float* __restrict__ G) {
  const int br = threadIdx.x;
  if (br >= 3) return;
  const float* crp = (br == 0) ? crx : (br == 1) ? cry : crz;
  const float* u3p = (br == 0) ? u3x : (br == 1) ? u3y : u3z;
  float* Gb = G + br * 128;

  // CR slots 0-7: (0,1)(2,3)(4,5)(6,7)(1,2)(3,4)(5,6)(3,5) -> (c,s, theta, theta/2)
  const int crIdx[8] = {0, 1, 2, 3, 4, 5, 6, 9};
#pragma unroll
  for (int i = 0; i < 8; ++i) {
    const float th = crp[crIdx[i]];
    float s, c;
    sincosf(0.5f * th, &s, &c);
    Gb[i * 8] = c;
    Gb[i * 8 + 1] = s;
    Gb[i * 8 + 2] = th;
    Gb[i * 8 + 3] = 0.5f * th;
  }
  c2 U1v[4], U3v[4], U5v[4], U7a[4], U7b[4], U3f[4], R[4], T[4], T2[4];
  u3m(u3p + 0, U1v);   // U3(1)
  u3m(u3p + 3, U3v);   // U3first(3)
  u3m(u3p + 6, U5v);   // U3(5)
  u3m(u3p + 9, U7a);   // U3first(7)
  u3m(u3p + 12, U3f);  // U3final(3)
  u3m(u3p + 15, U7b);  // U3final(7)
  storeM(Gb + 64, U1v);   // slot 8 : U3(1)
  storeM(Gb + 72, U3v);   // slot 9 : fused13 M
  rmat(br, crp[7], R);    // CR(1,3)
  mat2mul(R, U3v, T);
  storeM(Gb + 80, T);     // slot 10: fused13 N = R.U
  storeM(Gb + 88, U5v);   // slot 11: U3(5)
  mat2mul(U7b, U7a, T);
  storeM(Gb + 96, T);     // slot 12: big7 M = Uf.U
  rmat(br, crp[8], R);    // CR(5,7)
  mat2mul(R, U7a, T);
  mat2mul(U7b, T, T2);
  storeM(Gb + 104, T2);   // slot 13: big7 N = Uf.R.U
  // slot 14: measurement quadratic form of U3final(3)
  const float n00 = U3f[0].r * U3f[0].r + U3f[0].i * U3f[0].i;
  const float n01 = U3f[1].r * U3f[1].r + U3f[1].i * U3f[1].i;
  const float n10 = U3f[2].r * U3f[2].r + U3f[2].i * U3f[2].i;
  const float n11 = U3f[3].r * U3f[3].r + U3f[3].i * U3f[3].i;
  const c2 g01 = cmulc(U3f[0], U3f[1]);
  const c2 g23 = cmulc(U3f[2], U3f[3]);
  Gb[112] = n00 - n10;
  Gb[113] = n01 - n11;
  Gb[114] = 2.f * (g01.r - g23.r);
  Gb[115] = 2.f * (g01.i - g23.i);
}

// ============================ main ==========================================
__global__ __launch_bounds__(256) void qcnn_main(
    const float* __restrict__ x, const float* __restrict__ G,
    const float* __restrict__ w1, const float* __restrict__ b1,
    const float* __restrict__ w2, const float* __restrict__ b2,
    float* __restrict__ out, int B) {
  const int gid = blockIdx.x * blockDim.x + threadIdx.x;
  const int b = gid >> 4;
  const int gl = threadIdx.x & 15;
  if (b >= B) return;
  const float* xb = x + b * 8;

  const v2f fx = run_rx(xb, G, gl);
  const v2f fy = run_ry(xb, G + 128, gl);
  const v2f fz = run_rz(xb, G + 256, gl);

  // MLP head, lane-parallel over 12 hidden units within each 16-group
  const int j = (gl < 12) ? gl : 0;
  const float* w1r = w1 + j * 6;
  float a = b1[j];
  a += w1r[0] * fx.x + w1r[1] * fx.y + w1r[2] * fy.x + w1r[3] * fy.y +
       w1r[4] * fz.x + w1r[5] * fz.y;
  const float e = __expf(2.f * a);
  const float th = 1.f - 2.f * __builtin_amdgcn_rcpf(e + 1.f);
  float t = (gl < 12) ? w2[j] * th : 0.f;
  t += swz1<1>(t);
  t += swz1<2>(t);
  t += swz1<4>(t);
  t += swz1<8>(t);
  const float acc = t + b2[0];
  const float res = __builtin_amdgcn_rcpf(1.f + __expf(-acc));
  if (gl == 0) out[b] = res;
}

extern "C" void kernel_launch(void* const* d_in, const int* in_sizes, int n_in,
                              void* d_out, int out_size, void* d_ws,
                              size_t ws_size, hipStream_t stream) {
  const float* x = (const float*)d_in[0];
  const float* crx = (const float*)d_in[1];
  const float* u3x = (const float*)d_in[2];
  const float* cry = (const float*)d_in[3];
  const float* u3y = (const float*)d_in[4];
  const float* crz = (const float*)d_in[5];
  const float* u3z = (const float*)d_in[6];
  const float* w1 = (const float*)d_in[7];
  const float* b1 = (const float*)d_in[8];
  const float* w2 = (const float*)d_in[9];
  const float* b2 = (const float*)d_in[10];
  float* out = (float*)d_out;
  float* G = (float*)d_ws;  // 384 floats
  const int B = in_sizes[0] / 8;

  hipLaunchKernelGGL(qcnn_prep, dim3(1), dim3(64), 0, stream, crx, u3x, cry,
                     u3y, crz, u3z, G);
  const int threads = 256;
  const int blocks = (B * 16 + threads - 1) / threads;
  hipLaunchKernelGGL(qcnn_main, dim3(blocks), dim3(threads), 0, stream, x, G,
                     w1, b1, w2, b2, out, B);
}

// Round 8
// 107.687 us; speedup vs baseline: 1.0037x; 1.0037x over previous
//
#include <hip/hip_runtime.h>
#include <math.h>

// ---------------------------------------------------------------------------
// QCNN_Diff R8 (instrumented): R7 algorithm unchanged; grid halved, each
// 16-lane group runs TWO elements sequentially so qcnn_main (~78us) surfaces
// in the rocprof top-5 above the 40us harness poison fills -> read its
// VGPR_Count / VALUBusy / SQ_LDS_BANK_CONFLICT to split theory T1 (occupancy,
// VGPR>64) from T2 (per-gate s_load lgkm stalls, VALUBusy<50%).
// slot bits: q3->S0 q7->S1 q5->S2 q1->S3; lane bits: q0->L0 q2->L1 q4->L2 q6->L3
// ---------------------------------------------------------------------------

typedef float v2f __attribute__((ext_vector_type(2)));

__device__ __forceinline__ v2f mk2(float a, float b) { v2f r; r.x = a; r.y = b; return r; }
__device__ __forceinline__ v2f ld2(const float* __restrict__ p) { return *(const v2f*)p; }

// ---- VOP3P primitives, VGPR x VGPR -----------------------------------------
__device__ __forceinline__ v2f pk_mul_s(v2f a, v2f b) { v2f d;
  asm("v_pk_mul_f32 %0, %1, %2 op_sel:[0,0] op_sel_hi:[0,1]" : "=v"(d) : "v"(a), "v"(b)); return d; }
__device__ __forceinline__ v2f pk_fma_irot(v2f a, v2f b, v2f c) { v2f d;
  asm("v_pk_fma_f32 %0, %1, %2, %3 op_sel:[1,1,0] op_sel_hi:[1,0,1] neg_lo:[0,1,0]" : "=v"(d) : "v"(a), "v"(b), "v"(c)); return d; }
__device__ __forceinline__ v2f cmul(v2f a, v2f b) { return pk_fma_irot(a, b, pk_mul_s(a, b)); }
__device__ __forceinline__ v2f pk_mul_swap(v2f a, v2f b) { v2f d;
  asm("v_pk_mul_f32 %0, %1, %2 op_sel:[1,0] op_sel_hi:[0,1]" : "=v"(d) : "v"(a), "v"(b)); return d; }

// ---- VOP3P primitives, SGPR (wave-uniform) first operand -------------------
__device__ __forceinline__ v2f pk_mul_sM(v2f M, v2f b) { v2f d;
  asm("v_pk_mul_f32 %0, %1, %2 op_sel:[0,0] op_sel_hi:[0,1]" : "=v"(d) : "s"(M), "v"(b)); return d; }
__device__ __forceinline__ v2f pk_fma_sloM(v2f M, v2f b, v2f c) { v2f d;
  asm("v_pk_fma_f32 %0, %1, %2, %3 op_sel:[0,0,0] op_sel_hi:[0,1,1]" : "=v"(d) : "s"(M), "v"(b), "v"(c)); return d; }
__device__ __forceinline__ v2f pk_fma_shiM(v2f M, v2f b, v2f c) { v2f d;
  asm("v_pk_fma_f32 %0, %1, %2, %3 op_sel:[1,0,0] op_sel_hi:[1,1,1]" : "=v"(d) : "s"(M), "v"(b), "v"(c)); return d; }
__device__ __forceinline__ v2f pk_fma_shi_negM(v2f M, v2f b, v2f c) { v2f d;
  asm("v_pk_fma_f32 %0, %1, %2, %3 op_sel:[1,0,0] op_sel_hi:[1,1,1] neg_lo:[1,0,0] neg_hi:[1,0,0]" : "=v"(d) : "s"(M), "v"(b), "v"(c)); return d; }
__device__ __forceinline__ v2f pk_fma_rotM(v2f M, v2f b, v2f c) { v2f d;
  asm("v_pk_fma_f32 %0, %1, %2, %3 op_sel:[1,1,0] op_sel_hi:[1,0,1] neg_hi:[0,1,0]" : "=v"(d) : "s"(M), "v"(b), "v"(c)); return d; }
__device__ __forceinline__ v2f pk_fma_irotM(v2f M, v2f b, v2f c) { v2f d;
  asm("v_pk_fma_f32 %0, %1, %2, %3 op_sel:[1,1,0] op_sel_hi:[1,0,1] neg_lo:[0,1,0]" : "=v"(d) : "s"(M), "v"(b), "v"(c)); return d; }

template <int MASK>
__device__ __forceinline__ float swz1(float v) {
  constexpr int pat = (MASK << 10) | 0x1F;  // xor-mode
  return __int_as_float(__builtin_amdgcn_ds_swizzle(__float_as_int(v), pat));
}
template <int MASK>
__device__ __forceinline__ v2f swz2(v2f v) {
  v2f r; r.x = swz1<MASK>(v.x); r.y = swz1<MASK>(v.y); return r;
}

// ---- u3 row: ua*a + ub*b, matrices from SGPRs ------------------------------
template <bool A_REAL>
__device__ __forceinline__ v2f u3row_s(v2f ua, v2f ub, v2f a, v2f b) {
  v2f t = pk_mul_sM(ua, a);
  if constexpr (!A_REAL) t = pk_fma_irotM(ua, a, t);
  t = pk_fma_sloM(ub, b, t);
  return pk_fma_irotM(ub, b, t);
}

template <int SB>
__device__ __forceinline__ void u3_apply(v2f w[16], const float* __restrict__ p) {
  const v2f M0 = ld2(p), M1 = ld2(p + 2), M2 = ld2(p + 4), M3 = ld2(p + 6);
#pragma unroll
  for (int s0 = 0; s0 < 16; ++s0) {
    if (s0 & (1 << SB)) continue;
    const int s1 = s0 | (1 << SB);
    const v2f a = w[s0], b = w[s1];
    w[s0] = u3row_s<true>(M0, M1, a, b);
    w[s1] = u3row_s<false>(M3, M2, b, a);
  }
}

template <int SB, int CB, bool M00R>
__device__ __forceinline__ void u3_sel(v2f w[16], const float* __restrict__ pM,
                                       const float* __restrict__ pN) {
  const v2f M0 = ld2(pM), M1 = ld2(pM + 2), M2 = ld2(pM + 4), M3 = ld2(pM + 6);
  const v2f N0 = ld2(pN), N1 = ld2(pN + 2), N2 = ld2(pN + 4), N3 = ld2(pN + 6);
#pragma unroll
  for (int s0 = 0; s0 < 16; ++s0) {
    if (s0 & (1 << SB)) continue;
    const int s1 = s0 | (1 << SB);
    const v2f a = w[s0], b = w[s1];
    if ((s0 >> CB) & 1) {
      w[s0] = u3row_s<false>(N0, N1, a, b);
      w[s1] = u3row_s<false>(N3, N2, b, a);
    } else {
      w[s0] = u3row_s<M00R>(M0, M1, a, b);
      w[s1] = u3row_s<false>(M3, M2, b, a);
    }
  }
}

template <int SB, int LB>
__device__ __forceinline__ void crx_Sc_Lt(v2f w[16], v2f cs) {
#pragma unroll
  for (int s = 0; s < 16; ++s) {
    if (!(s & (1 << SB))) continue;
    const v2f p = swz2<(1 << LB)>(w[s]);
    w[s] = pk_fma_rotM(cs, p, pk_mul_sM(cs, w[s]));
  }
}

template <int SB, int LB>
__device__ __forceinline__ void cr_ry_r(float w[16], v2f cs, int gl) {
  const bool tb = (gl >> LB) & 1;
  const float Ky = tb ? cs.y : -cs.y;
#pragma unroll
  for (int s = 0; s < 16; ++s) {
    if (!(s & (1 << SB))) continue;
    const float p = swz1<(1 << LB)>(w[s]);
    w[s] = __builtin_fmaf(Ky, p, cs.x * w[s]);
  }
}

template <int KIND, int SBc, int SBt>
__device__ __forceinline__ void cr_Sc_St(v2f w[16], v2f cs) {
#pragma unroll
  for (int s0 = 0; s0 < 16; ++s0) {
    if (!(s0 & (1 << SBc))) continue;
    if constexpr (KIND == 2) {
      const v2f t = pk_mul_sM(cs, w[s0]);
      w[s0] = (s0 & (1 << SBt)) ? pk_fma_irotM(cs, w[s0], t)
                                : pk_fma_rotM(cs, w[s0], t);
    } else {
      if (s0 & (1 << SBt)) continue;
      const int s1 = s0 | (1 << SBt);
      const v2f a = w[s0], b = w[s1];
      if constexpr (KIND == 0) {
        w[s0] = pk_fma_rotM(cs, b, pk_mul_sM(cs, a));
        w[s1] = pk_fma_rotM(cs, a, pk_mul_sM(cs, b));
      } else {
        w[s0] = pk_fma_shi_negM(cs, b, pk_mul_sM(cs, a));
        w[s1] = pk_fma_shiM(cs, a, pk_mul_sM(cs, b));
      }
    }
  }
}

template <int SB>
__device__ __forceinline__ void u3_lift(v2f w[16], const float wr[16],
                                        const float* __restrict__ p) {
  const v2f M0 = ld2(p), M1 = ld2(p + 2), M2 = ld2(p + 4), M3 = ld2(p + 6);
#pragma unroll
  for (int s0 = 0; s0 < 16; ++s0) {
    if (s0 & (1 << SB)) continue;
    const int s1 = s0 | (1 << SB);
    const float a = wr[s0], b = wr[s1];
    w[s0] = mk2(__builtin_fmaf(a, M0.x, b * M1.x), b * M1.y);
    w[s1] = mk2(__builtin_fmaf(a, M2.x, b * M3.x),
                __builtin_fmaf(a, M2.y, b * M3.y));
  }
}

__device__ __forceinline__ v2f measure(v2f w[16], const float* __restrict__ q) {
  const v2f qa = ld2(q);      // (alpha, beta)
  const v2f qg = ld2(q + 2);  // (gr, gi)
  float z3a = 0.f, z3b = 0.f, z7p = 0.f, z7m = 0.f;
#pragma unroll
  for (int s0 = 0; s0 < 16; s0 += 2) {
    const v2f a = w[s0], b = w[s0 + 1];
    const v2f t1 = a * b, t2 = pk_mul_swap(a, b), t3 = a * a, t4 = b * b;
    const float r = t1.x + t1.y;
    const float m = t2.x - t2.y;
    const float na = t3.x + t3.y;
    const float nb = t4.x + t4.y;
    z3a = __builtin_fmaf(qa.x, na, z3a);
    z3b = __builtin_fmaf(qa.y, nb, z3b);
    z3a = __builtin_fmaf(qg.x, r, z3a);
    z3b = __builtin_fmaf(-qg.y, m, z3b);
    const float nn = na + nb;
    if (s0 & 2) z7m += nn; else z7p += nn;
  }
  float z3 = z3a + z3b, z7 = z7p - z7m;
  z3 += swz1<1>(z3); z7 += swz1<1>(z7);
  z3 += swz1<2>(z3); z7 += swz1<2>(z7);
  z3 += swz1<4>(z3); z7 += swz1<4>(z7);
  z3 += swz1<8>(z3); z7 += swz1<8>(z7);
  return mk2(z3, z7);
}

template <int KIND>
__device__ __forceinline__ v2f tail_common(v2f w[16], const float* __restrict__ Gb) {
  u3_sel<0, 3, true>(w, Gb + 72, Gb + 80);    // U3first(3) / R13.U3first(3)
  u3_apply<2>(w, Gb + 88);                    // U3(5)
  u3_sel<1, 2, false>(w, Gb + 96, Gb + 104);  // Uf7.U7 / Uf7.R57.U7
  cr_Sc_St<KIND, 0, 2>(w, ld2(Gb + 56));      // CR(3,5)
  return measure(w, Gb + 112);                // folds U3final(3)
}

__device__ __forceinline__ void load_sincos(const float* __restrict__ xb,
                                            float sn[8], float cn[8]) {
  const float4 xlo = ((const float4*)xb)[0];
  const float4 xhi = ((const float4*)xb)[1];
  const float xq[8] = {xlo.x, xlo.y, xlo.z, xlo.w, xhi.x, xhi.y, xhi.z, xhi.w};
#pragma unroll
  for (int q = 0; q < 8; ++q) __sincosf(0.5f * xq[q], &sn[q], &cn[q]);
}

// ============================ branch heads ==================================
__device__ __forceinline__ v2f run_rx(const float* __restrict__ xb,
                                      const float* __restrict__ Gb, int gl) {
  float sn[8], cn[8];
  load_sincos(xb, sn, cn);
  const bool l0 = gl & 1, l1 = (gl >> 1) & 1, l2 = (gl >> 2) & 1, l3 = (gl >> 3) & 1;
  v2f pa[4], pb[4];
#pragma unroll
  for (int pr = 0; pr < 4; ++pr) {
    const bool lh = (pr == 0) ? l0 : (pr == 1) ? l1 : (pr == 2) ? l2 : l3;
    const float c = Gb[pr * 8], s = Gb[pr * 8 + 1];
    const float uc = lh ? sn[2 * pr] : cn[2 * pr];
    const float b0 = uc * cn[2 * pr + 1], b1 = uc * sn[2 * pr + 1];
    const float Kx = lh ? c : 1.f;
    const float Kyn = lh ? -s : 0.f;
    pa[pr] = mk2(Kx * b0, Kyn * b1);
    pb[pr] = mk2(Kx * b1, Kyn * b0);
  }
  v2f A[4] = {cmul(pa[0], pa[2]), cmul(pa[0], pb[2]), cmul(pb[0], pa[2]), cmul(pb[0], pb[2])};
  v2f Bv[4] = {cmul(pa[3], pa[1]), cmul(pa[3], pb[1]), cmul(pb[3], pa[1]), cmul(pb[3], pb[1])};
  v2f w[16];
#pragma unroll
  for (int s = 0; s < 16; ++s) w[s] = cmul(A[s >> 2], Bv[s & 3]);
  crx_Sc_Lt<3, 1>(w, ld2(Gb + 32));  // (1,2)
  crx_Sc_Lt<0, 2>(w, ld2(Gb + 40));  // (3,4)
  crx_Sc_Lt<2, 3>(w, ld2(Gb + 48));  // (5,6)
  u3_apply<3>(w, Gb + 64);           // U3(1)
  return tail_common<0>(w, Gb);
}

__device__ __forceinline__ v2f run_ry(const float* __restrict__ xb,
                                      const float* __restrict__ Gb, int gl) {
  float sn[8], cn[8];
  load_sincos(xb, sn, cn);
  const bool l0 = gl & 1, l1 = (gl >> 1) & 1, l2 = (gl >> 2) & 1, l3 = (gl >> 3) & 1;
  float pa[4], pb[4];
#pragma unroll
  for (int pr = 0; pr < 4; ++pr) {
    const bool lh = (pr == 0) ? l0 : (pr == 1) ? l1 : (pr == 2) ? l2 : l3;
    const float c = Gb[pr * 8], s = Gb[pr * 8 + 1];
    const float uc = lh ? sn[2 * pr] : cn[2 * pr];
    const float b0 = uc * cn[2 * pr + 1], b1 = uc * sn[2 * pr + 1];
    const float Kx = lh ? c : 1.f;
    const float Ky = lh ? s : 0.f;
    pa[pr] = Kx * b0 - Ky * b1;
    pb[pr] = Ky * b0 + Kx * b1;
  }
  const float A[4] = {pa[0] * pa[2], pa[0] * pb[2], pb[0] * pa[2], pb[0] * pb[2]};
  const float Bv[4] = {pa[3] * pa[1], pa[3] * pb[1], pb[3] * pa[1], pb[3] * pb[1]};
  float wr[16];
#pragma unroll
  for (int s = 0; s < 16; ++s) wr[s] = A[s >> 2] * Bv[s & 3];
  cr_ry_r<3, 1>(wr, ld2(Gb + 32), gl);
  cr_ry_r<0, 2>(wr, ld2(Gb + 40), gl);
  cr_ry_r<2, 3>(wr, ld2(Gb + 48), gl);
  v2f w[16];
  u3_lift<3>(w, wr, Gb + 64);        // U3(1), real input
  return tail_common<1>(w, Gb);
}

__device__ __forceinline__ v2f run_rz(const float* __restrict__ xb,
                                      const float* __restrict__ Gb, int gl) {
  float sn[8], cn[8];
  load_sincos(xb, sn, cn);
  const bool l0 = gl & 1, l1 = (gl >> 1) & 1, l2 = (gl >> 2) & 1, l3 = (gl >> 3) & 1;
  const float u0 = l0 ? sn[0] : cn[0];
  const float u2 = l1 ? sn[2] : cn[2];
  const float u4 = l2 ? sn[4] : cn[4];
  const float u6 = l3 ? sn[6] : cn[6];
  const float P = (u0 * u2) * (u4 * u6);
  float v01[4], v23[4];
  v01[0] = P * (cn[3] * cn[7]); v01[1] = P * (sn[3] * cn[7]);
  v01[2] = P * (cn[3] * sn[7]); v01[3] = P * (sn[3] * sn[7]);
  v23[0] = cn[5] * cn[1]; v23[1] = sn[5] * cn[1];
  v23[2] = cn[5] * sn[1]; v23[3] = sn[5] * sn[1];
  const float t0 = Gb[2], h0 = Gb[3];
  const float t1 = Gb[10], h1 = Gb[11];
  const float t2 = Gb[18], h2 = Gb[19];
  const float t3 = Gb[26], h3 = Gb[27];
  const float h4 = Gb[35], h5 = Gb[43], h6 = Gb[51];
  const float kk0 = (l1 ? t1 : 0.f) + (l2 ? h5 : -h5);
  const float kk1 = (l3 ? t3 : 0.f);
  const float kk2 = (l2 ? t2 : 0.f) + (l3 ? h6 : -h6);
  const float kk3 = (l0 ? t0 : 0.f) + (l1 ? h4 : -h4);
  const float aa = -((l0 ? h0 : 0.f) + (l1 ? h1 : 0.f) + (l2 ? h2 : 0.f) + (l3 ? h3 : 0.f));
  v2f w[16];
#pragma unroll
  for (int s = 0; s < 16; ++s) {
    float phv = aa;
    if (s & 1) phv += kk0;
    if (s & 2) phv += kk1;
    if (s & 4) phv += kk2;
    if (s & 8) phv += kk3;
    float sp, cp;
    __sincosf(phv, &sp, &cp);
    const float e = v01[s & 3] * v23[s >> 2];
    w[s] = mk2(e * cp, e * sp);
  }
  u3_apply<3>(w, Gb + 64);           // U3(1)
  return tail_common<2>(w, Gb);
}

// ============================ prep ==========================================
struct c2 { float r, i; };
__device__ __forceinline__ c2 cmulh(c2 a, c2 b) { return {a.r * b.r - a.i * b.i, a.r * b.i + a.i * b.r}; }
__device__ __forceinline__ c2 cmulc(c2 a, c2 b) { return {a.r * b.r + a.i * b.i, a.i * b.r - a.r * b.i}; }
__device__ __forceinline__ c2 caddh(c2 a, c2 b) { return {a.r + b.r, a.i + b.i}; }
__device__ void mat2mul(const c2 A[4], const c2 B[4], c2 C[4]) {
  C[0] = caddh(cmulh(A[0], B[0]), cmulh(A[1], B[2]));
  C[1] = caddh(cmulh(A[0], B[1]), cmulh(A[1], B[3]));
  C[2] = caddh(cmulh(A[2], B[0]), cmulh(A[3], B[2]));
  C[3] = caddh(cmulh(A[2], B[1]), cmulh(A[3], B[3]));
}
__device__ void u3m(const float* p, c2 M[4]) {
  float st, ct, sp, cp, sl, cl;
  sincosf(0.5f * p[0], &st, &ct);
  sincosf(p[1], &sp, &cp);
  sincosf(p[2], &sl, &cl);
  M[0] = {ct, 0.f};
  M[1] = {-cl * st, -sl * st};
  M[2] = {cp * st, sp * st};
  M[3] = {(cp * cl - sp * sl) * ct, (sp * cl + cp * sl) * ct};
}
__device__ void rmat(int kind, float th, c2 R[4]) {
  float s, c;
  sincosf(0.5f * th, &s, &c);
  if (kind == 0) { R[0] = {c, 0.f}; R[1] = {0.f, -s}; R[2] = {0.f, -s}; R[3] = {c, 0.f}; }
  else if (kind == 1) { R[0] = {c, 0.f}; R[1] = {-s, 0.f}; R[2] = {s, 0.f}; R[3] = {c, 0.f}; }
  else { R[0] = {c, -s}; R[1] = {0.f, 0.f}; R[2] = {0.f, 0.f}; R[3] = {c, s}; }
}
__device__ void storeM(float* dst, const c2 M[4]) {
#pragma unroll
  for (int j = 0; j < 4; ++j) { dst[2 * j] = M[j].r; dst[2 * j + 1] = M[j].i; }
}

__global__ void qcnn_prep(const float* __restrict__ crx, const float* __restrict__ u3x,
                          const float* __restrict__ cry, const float* __restrict__ u3y,
                          const float* __restrict__ crz, const float* __restrict__ u3z,
                          float* __restrict__ G) {
  const int br = threadIdx.x;
  if (br >= 3) return;
  const float* crp = (br == 0) ? crx : (br == 1) ? cry : crz;
  const float* u3p = (br == 0) ? u3x : (br == 1) ? u3y : u3z;
  float* Gb = G + br * 128;

  const int crIdx[8] = {0, 1, 2, 3, 4, 5, 6, 9};
#pragma unroll
  for (int i = 0; i < 8; ++i) {
    const float th = crp[crIdx[i]];
    float s, c;
    sincosf(0.5f * th, &s, &c);
    Gb[i * 8] = c;
    Gb[i * 8 + 1] = s;
    Gb[i * 8 + 2] = th;
    Gb[i * 8 + 3] = 0.5f * th;
  }
  c2 U1v[4], U3v[4], U5v[4], U7a[4], U7b[4], U3f[4], R[4], T[4], T2[4];
  u3m(u3p + 0, U1v);
  u3m(u3p + 3, U3v);
  u3m(u3p + 6, U5v);
  u3m(u3p + 9, U7a);
  u3m(u3p + 12, U3f);
  u3m(u3p + 15, U7b);
  storeM(Gb + 64, U1v);
  storeM(Gb + 72, U3v);
  rmat(br, crp[7], R);
  mat2mul(R, U3v, T);
  storeM(Gb + 80, T);
  storeM(Gb + 88, U5v);
  mat2mul(U7b, U7a, T);
  storeM(Gb + 96, T);
  rmat(br, crp[8], R);
  mat2mul(R, U7a, T);
  mat2mul(U7b, T, T2);
  storeM(Gb + 104, T2);
  const float n00 = U3f[0].r * U3f[0].r + U3f[0].i * U3f[0].i;
  const float n01 = U3f[1].r * U3f[1].r + U3f[1].i * U3f[1].i;
  const float n10 = U3f[2].r * U3f[2].r + U3f[2].i * U3f[2].i;
  const float n11 = U3f[3].r * U3f[3].r + U3f[3].i * U3f[3].i;
  const c2 g01 = cmulc(U3f[0], U3f[1]);
  const c2 g23 = cmulc(U3f[2], U3f[3]);
  Gb[112] = n00 - n10;
  Gb[113] = n01 - n11;
  Gb[114] = 2.f * (g01.r - g23.r);
  Gb[115] = 2.f * (g01.i - g23.i);
}

// ============================ main ==========================================
__global__ __launch_bounds__(256) void qcnn_main(
    const float* __restrict__ x, const float* __restrict__ G,
    const float* __restrict__ w1, const float* __restrict__ b1,
    const float* __restrict__ w2, const float* __restrict__ b2,
    float* __restrict__ out, int B) {
  const int gid = blockIdx.x * blockDim.x + threadIdx.x;
  const int grp = gid >> 4;  // 16-lane group; handles 2 elements
  const int gl = threadIdx.x & 15;

#pragma unroll 1
  for (int e = 0; e < 2; ++e) {
    const int b = grp * 2 + e;
    if (b >= B) continue;
    const float* xb = x + b * 8;

    const v2f fx = run_rx(xb, G, gl);
    const v2f fy = run_ry(xb, G + 128, gl);
    const v2f fz = run_rz(xb, G + 256, gl);

    const int j = (gl < 12) ? gl : 0;
    const float* w1r = w1 + j * 6;
    float a = b1[j];
    a += w1r[0] * fx.x + w1r[1] * fx.y + w1r[2] * fy.x + w1r[3] * fy.y +
         w1r[4] * fz.x + w1r[5] * fz.y;
    const float ev = __expf(2.f * a);
    const float th = 1.f - 2.f * __builtin_amdgcn_rcpf(ev + 1.f);
    float t = (gl < 12) ? w2[j] * th : 0.f;
    t += swz1<1>(t);
    t += swz1<2>(t);
    t += swz1<4>(t);
    t += swz1<8>(t);
    const float acc = t + b2[0];
    const float res = __builtin_amdgcn_rcpf(1.f + __expf(-acc));
    if (gl == 0) out[b] = res;
  }
}

extern "C" void kernel_launch(void* const* d_in, const int* in_sizes, int n_in,
                              void* d_out, int out_size, void* d_ws,
                              size_t ws_size, hipStream_t stream) {
  const float* x = (const float*)d_in[0];
  const float* crx = (const float*)d_in[1];
  const float* u3x = (const float*)d_in[2];
  const float* cry = (const float*)d_in[3];
  const float* u3y = (const float*)d_in[4];
  const float* crz = (const float*)d_in[5];
  const float* u3z = (const float*)d_in[6];
  const float* w1 = (const float*)d_in[7];
  const float* b1 = (const float*)d_in[8];
  const float* w2 = (const float*)d_in[9];
  const float* b2 = (const float*)d_in[10];
  float* out = (float*)d_out;
  float* G = (float*)d_ws;  // 384 floats
  const int B = in_sizes[0] / 8;

  hipLaunchKernelGGL(qcnn_prep, dim3(1), dim3(64), 0, stream, crx, u3x, cry,
                     u3y, crz, u3z, G);
  const int ngroups = (B + 1) / 2;                    // 2 elements per group
  const int threads = 256;
  const int blocks = (ngroups * 16 + threads - 1) / threads;
  hipLaunchKernelGGL(qcnn_main, dim3(blocks), dim3(threads), 0, stream, x, G,
                     w1, b1, w2, b2, out, B);
}

// Round 9
// 104.726 us; speedup vs baseline: 1.0321x; 1.0283x over previous
//
#include <hip/hip_runtime.h>
#include <math.h>

// ---------------------------------------------------------------------------
// QCNN_Diff R9: latency-bound fix (R8 evidence: VGPR=36, VALUBusy=44%@4waves,
// 2x work per wave cost only +17%). TWO elements per 16-lane group, run
// INTERLEAVED through every gate (w[32], element = bit 4 of the index).
// - every stall window gets a second independent dependency chain
// - all wave-uniform setup (matrix s_loads, K folds, rz phase coeffs + the 16
//   rz sincos calls) shared between the two elements
// Algorithm identical to R7 (validated absmax 0.0).
// slot bits: q3->S0 q7->S1 q5->S2 q1->S3; lane bits: q0->L0 q2->L1 q4->L2 q6->L3
// ---------------------------------------------------------------------------

typedef float v2f __attribute__((ext_vector_type(2)));

__device__ __forceinline__ v2f mk2(float a, float b) { v2f r; r.x = a; r.y = b; return r; }
__device__ __forceinline__ v2f ld2(const float* __restrict__ p) { return *(const v2f*)p; }

// ---- VOP3P primitives, VGPR x VGPR -----------------------------------------
__device__ __forceinline__ v2f pk_mul_s(v2f a, v2f b) { v2f d;
  asm("v_pk_mul_f32 %0, %1, %2 op_sel:[0,0] op_sel_hi:[0,1]" : "=v"(d) : "v"(a), "v"(b)); return d; }
__device__ __forceinline__ v2f pk_fma_irot(v2f a, v2f b, v2f c) { v2f d;
  asm("v_pk_fma_f32 %0, %1, %2, %3 op_sel:[1,1,0] op_sel_hi:[1,0,1] neg_lo:[0,1,0]" : "=v"(d) : "v"(a), "v"(b), "v"(c)); return d; }
__device__ __forceinline__ v2f cmul(v2f a, v2f b) { return pk_fma_irot(a, b, pk_mul_s(a, b)); }
__device__ __forceinline__ v2f pk_mul_swap(v2f a, v2f b) { v2f d;
  asm("v_pk_mul_f32 %0, %1, %2 op_sel:[1,0] op_sel_hi:[0,1]" : "=v"(d) : "v"(a), "v"(b)); return d; }

// ---- VOP3P primitives, SGPR (wave-uniform) first operand -------------------
__device__ __forceinline__ v2f pk_mul_sM(v2f M, v2f b) { v2f d;
  asm("v_pk_mul_f32 %0, %1, %2 op_sel:[0,0] op_sel_hi:[0,1]" : "=v"(d) : "s"(M), "v"(b)); return d; }
__device__ __forceinline__ v2f pk_fma_sloM(v2f M, v2f b, v2f c) { v2f d;
  asm("v_pk_fma_f32 %0, %1, %2, %3 op_sel:[0,0,0] op_sel_hi:[0,1,1]" : "=v"(d) : "s"(M), "v"(b), "v"(c)); return d; }
__device__ __forceinline__ v2f pk_fma_shiM(v2f M, v2f b, v2f c) { v2f d;
  asm("v_pk_fma_f32 %0, %1, %2, %3 op_sel:[1,0,0] op_sel_hi:[1,1,1]" : "=v"(d) : "s"(M), "v"(b), "v"(c)); return d; }
__device__ __forceinline__ v2f pk_fma_shi_negM(v2f M, v2f b, v2f c) { v2f d;
  asm("v_pk_fma_f32 %0, %1, %2, %3 op_sel:[1,0,0] op_sel_hi:[1,1,1] neg_lo:[1,0,0] neg_hi:[1,0,0]" : "=v"(d) : "s"(M), "v"(b), "v"(c)); return d; }
__device__ __forceinline__ v2f pk_fma_rotM(v2f M, v2f b, v2f c) { v2f d;
  asm("v_pk_fma_f32 %0, %1, %2, %3 op_sel:[1,1,0] op_sel_hi:[1,0,1] neg_hi:[0,1,0]" : "=v"(d) : "s"(M), "v"(b), "v"(c)); return d; }
__device__ __forceinline__ v2f pk_fma_irotM(v2f M, v2f b, v2f c) { v2f d;
  asm("v_pk_fma_f32 %0, %1, %2, %3 op_sel:[1,1,0] op_sel_hi:[1,0,1] neg_lo:[0,1,0]" : "=v"(d) : "s"(M), "v"(b), "v"(c)); return d; }

template <int MASK>
__device__ __forceinline__ float swz1(float v) {
  constexpr int pat = (MASK << 10) | 0x1F;  // xor-mode
  return __int_as_float(__builtin_amdgcn_ds_swizzle(__float_as_int(v), pat));
}
template <int MASK>
__device__ __forceinline__ v2f swz2(v2f v) {
  v2f r; r.x = swz1<MASK>(v.x); r.y = swz1<MASK>(v.y); return r;
}

// ---- u3 row: ua*a + ub*b, matrices from SGPRs ------------------------------
template <bool A_REAL>
__device__ __forceinline__ v2f u3row_s(v2f ua, v2f ub, v2f a, v2f b) {
  v2f t = pk_mul_sM(ua, a);
  if constexpr (!A_REAL) t = pk_fma_irotM(ua, a, t);
  t = pk_fma_sloM(ub, b, t);
  return pk_fma_irotM(ub, b, t);
}

// All gate helpers operate on w[32] = two interleaved elements; slot-pair
// bits are the low 4 index bits, element = bit 4, so i|(1<<SB) stays in-element.
template <int SB>
__device__ __forceinline__ void u3_apply(v2f w[32], const float* __restrict__ p) {
  const v2f M0 = ld2(p), M1 = ld2(p + 2), M2 = ld2(p + 4), M3 = ld2(p + 6);
#pragma unroll
  for (int i = 0; i < 32; ++i) {
    if (i & (1 << SB)) continue;
    const int i1 = i | (1 << SB);
    const v2f a = w[i], b = w[i1];
    w[i] = u3row_s<true>(M0, M1, a, b);
    w[i1] = u3row_s<false>(M3, M2, b, a);
  }
}

template <int SB, int CB, bool M00R>
__device__ __forceinline__ void u3_sel(v2f w[32], const float* __restrict__ pM,
                                       const float* __restrict__ pN) {
  const v2f M0 = ld2(pM), M1 = ld2(pM + 2), M2 = ld2(pM + 4), M3 = ld2(pM + 6);
  const v2f N0 = ld2(pN), N1 = ld2(pN + 2), N2 = ld2(pN + 4), N3 = ld2(pN + 6);
#pragma unroll
  for (int i = 0; i < 32; ++i) {
    if (i & (1 << SB)) continue;
    const int i1 = i | (1 << SB);
    const v2f a = w[i], b = w[i1];
    if ((i >> CB) & 1) {
      w[i] = u3row_s<false>(N0, N1, a, b);
      w[i1] = u3row_s<false>(N3, N2, b, a);
    } else {
      w[i] = u3row_s<M00R>(M0, M1, a, b);
      w[i1] = u3row_s<false>(M3, M2, b, a);
    }
  }
}

template <int SB, int LB>
__device__ __forceinline__ void crx_Sc_Lt(v2f w[32], v2f cs) {
#pragma unroll
  for (int i = 0; i < 32; ++i) {
    if (!(i & (1 << SB))) continue;
    const v2f p = swz2<(1 << LB)>(w[i]);
    w[i] = pk_fma_rotM(cs, p, pk_mul_sM(cs, w[i]));
  }
}

template <int SB, int LB>
__device__ __forceinline__ void cr_ry_r(float w[32], v2f cs, int gl) {
  const bool tb = (gl >> LB) & 1;
  const float Ky = tb ? cs.y : -cs.y;
#pragma unroll
  for (int i = 0; i < 32; ++i) {
    if (!(i & (1 << SB))) continue;
    const float p = swz1<(1 << LB)>(w[i]);
    w[i] = __builtin_fmaf(Ky, p, cs.x * w[i]);
  }
}

template <int KIND, int SBc, int SBt>
__device__ __forceinline__ void cr_Sc_St(v2f w[32], v2f cs) {
#pragma unroll
  for (int i = 0; i < 32; ++i) {
    if (!(i & (1 << SBc))) continue;
    if constexpr (KIND == 2) {
      const v2f t = pk_mul_sM(cs, w[i]);
      w[i] = (i & (1 << SBt)) ? pk_fma_irotM(cs, w[i], t)
                              : pk_fma_rotM(cs, w[i], t);
    } else {
      if (i & (1 << SBt)) continue;
      const int i1 = i | (1 << SBt);
      const v2f a = w[i], b = w[i1];
      if constexpr (KIND == 0) {
        w[i] = pk_fma_rotM(cs, b, pk_mul_sM(cs, a));
        w[i1] = pk_fma_rotM(cs, a, pk_mul_sM(cs, b));
      } else {
        w[i] = pk_fma_shi_negM(cs, b, pk_mul_sM(cs, a));
        w[i1] = pk_fma_shiM(cs, a, pk_mul_sM(cs, b));
      }
    }
  }
}

template <int SB>
__device__ __forceinline__ void u3_lift(v2f w[32], const float wr[32],
                                        const float* __restrict__ p) {
  const v2f M0 = ld2(p), M1 = ld2(p + 2), M2 = ld2(p + 4), M3 = ld2(p + 6);
#pragma unroll
  for (int i = 0; i < 32; ++i) {
    if (i & (1 << SB)) continue;
    const int i1 = i | (1 << SB);
    const float a = wr[i], b = wr[i1];
    w[i] = mk2(__builtin_fmaf(a, M0.x, b * M1.x), b * M1.y);
    w[i1] = mk2(__builtin_fmaf(a, M2.x, b * M3.x),
                __builtin_fmaf(a, M2.y, b * M3.y));
  }
}

__device__ __forceinline__ void measure2(v2f w[32], const float* __restrict__ q,
                                         v2f res[2]) {
  const v2f qa = ld2(q);      // (alpha, beta)
  const v2f qg = ld2(q + 2);  // (gr, gi)
  float z3[2], z7[2];
#pragma unroll
  for (int e = 0; e < 2; ++e) {
    float z3a = 0.f, z3b = 0.f, z7p = 0.f, z7m = 0.f;
#pragma unroll
    for (int s0 = 0; s0 < 16; s0 += 2) {
      const v2f a = w[e * 16 + s0], b = w[e * 16 + s0 + 1];
      const v2f t1 = a * b, t2 = pk_mul_swap(a, b), t3 = a * a, t4 = b * b;
      const float r = t1.x + t1.y;
      const float m = t2.x - t2.y;
      const float na = t3.x + t3.y;
      const float nb = t4.x + t4.y;
      z3a = __builtin_fmaf(qa.x, na, z3a);
      z3b = __builtin_fmaf(qa.y, nb, z3b);
      z3a = __builtin_fmaf(qg.x, r, z3a);
      z3b = __builtin_fmaf(-qg.y, m, z3b);
      const float nn = na + nb;
      if (s0 & 2) z7m += nn; else z7p += nn;
    }
    z3[e] = z3a + z3b;
    z7[e] = z7p - z7m;
  }
  z3[0] += swz1<1>(z3[0]); z3[1] += swz1<1>(z3[1]); z7[0] += swz1<1>(z7[0]); z7[1] += swz1<1>(z7[1]);
  z3[0] += swz1<2>(z3[0]); z3[1] += swz1<2>(z3[1]); z7[0] += swz1<2>(z7[0]); z7[1] += swz1<2>(z7[1]);
  z3[0] += swz1<4>(z3[0]); z3[1] += swz1<4>(z3[1]); z7[0] += swz1<4>(z7[0]); z7[1] += swz1<4>(z7[1]);
  z3[0] += swz1<8>(z3[0]); z3[1] += swz1<8>(z3[1]); z7[0] += swz1<8>(z7[0]); z7[1] += swz1<8>(z7[1]);
  res[0] = mk2(z3[0], z7[0]);
  res[1] = mk2(z3[1], z7[1]);
}

template <int KIND>
__device__ __forceinline__ void tail_common(v2f w[32], const float* __restrict__ Gb,
                                            v2f res[2]) {
  u3_sel<0, 3, true>(w, Gb + 72, Gb + 80);    // U3first(3) / R13.U3first(3)
  u3_apply<2>(w, Gb + 88);                    // U3(5)
  u3_sel<1, 2, false>(w, Gb + 96, Gb + 104);  // Uf7.U7 / Uf7.R57.U7
  cr_Sc_St<KIND, 0, 2>(w, ld2(Gb + 56));      // CR(3,5)
  measure2(w, Gb + 112, res);                 // folds U3final(3)
}

__device__ __forceinline__ void load_sincos(const float* __restrict__ xb,
                                            float sn[8], float cn[8]) {
  const float4 xlo = ((const float4*)xb)[0];
  const float4 xhi = ((const float4*)xb)[1];
  const float xq[8] = {xlo.x, xlo.y, xlo.z, xlo.w, xhi.x, xhi.y, xhi.z, xhi.w};
#pragma unroll
  for (int q = 0; q < 8; ++q) __sincosf(0.5f * xq[q], &sn[q], &cn[q]);
}

// ============================ branch heads ==================================
__device__ __forceinline__ void run_rx(const float* __restrict__ xb0,
                                       const float* __restrict__ xb1,
                                       const float* __restrict__ Gb, int gl,
                                       v2f res[2]) {
  const bool l0 = gl & 1, l1 = (gl >> 1) & 1, l2 = (gl >> 2) & 1, l3 = (gl >> 3) & 1;
  v2f w[32];
#pragma unroll
  for (int e = 0; e < 2; ++e) {
    float sn[8], cn[8];
    load_sincos(e ? xb1 : xb0, sn, cn);
    v2f pa[4], pb[4];
#pragma unroll
    for (int pr = 0; pr < 4; ++pr) {
      const bool lh = (pr == 0) ? l0 : (pr == 1) ? l1 : (pr == 2) ? l2 : l3;
      const float c = Gb[pr * 8], s = Gb[pr * 8 + 1];
      const float uc = lh ? sn[2 * pr] : cn[2 * pr];
      const float b0 = uc * cn[2 * pr + 1], b1 = uc * sn[2 * pr + 1];
      const float Kx = lh ? c : 1.f;
      const float Kyn = lh ? -s : 0.f;
      pa[pr] = mk2(Kx * b0, Kyn * b1);
      pb[pr] = mk2(Kx * b1, Kyn * b0);
    }
    v2f A[4] = {cmul(pa[0], pa[2]), cmul(pa[0], pb[2]), cmul(pb[0], pa[2]), cmul(pb[0], pb[2])};
    v2f Bv[4] = {cmul(pa[3], pa[1]), cmul(pa[3], pb[1]), cmul(pb[3], pa[1]), cmul(pb[3], pb[1])};
#pragma unroll
    for (int s = 0; s < 16; ++s) w[e * 16 + s] = cmul(A[s >> 2], Bv[s & 3]);
  }
  crx_Sc_Lt<3, 1>(w, ld2(Gb + 32));  // (1,2)
  crx_Sc_Lt<0, 2>(w, ld2(Gb + 40));  // (3,4)
  crx_Sc_Lt<2, 3>(w, ld2(Gb + 48));  // (5,6)
  u3_apply<3>(w, Gb + 64);           // U3(1)
  tail_common<0>(w, Gb, res);
}

__device__ __forceinline__ void run_ry(const float* __restrict__ xb0,
                                       const float* __restrict__ xb1,
                                       const float* __restrict__ Gb, int gl,
                                       v2f res[2]) {
  const bool l0 = gl & 1, l1 = (gl >> 1) & 1, l2 = (gl >> 2) & 1, l3 = (gl >> 3) & 1;
  float wr[32];
#pragma unroll
  for (int e = 0; e < 2; ++e) {
    float sn[8], cn[8];
    load_sincos(e ? xb1 : xb0, sn, cn);
    float pa[4], pb[4];
#pragma unroll
    for (int pr = 0; pr < 4; ++pr) {
      const bool lh = (pr == 0) ? l0 : (pr == 1) ? l1 : (pr == 2) ? l2 : l3;
      const float c = Gb[pr * 8], s = Gb[pr * 8 + 1];
      const float uc = lh ? sn[2 * pr] : cn[2 * pr];
      const float b0 = uc * cn[2 * pr + 1], b1 = uc * sn[2 * pr + 1];
      const float Kx = lh ? c : 1.f;
      const float Ky = lh ? s : 0.f;
      pa[pr] = Kx * b0 - Ky * b1;
      pb[pr] = Ky * b0 + Kx * b1;
    }
    const float A[4] = {pa[0] * pa[2], pa[0] * pb[2], pb[0] * pa[2], pb[0] * pb[2]};
    const float Bv[4] = {pa[3] * pa[1], pa[3] * pb[1], pb[3] * pa[1], pb[3] * pb[1]};
#pragma unroll
    for (int s = 0; s < 16; ++s) wr[e * 16 + s] = A[s >> 2] * Bv[s & 3];
  }
  cr_ry_r<3, 1>(wr, ld2(Gb + 32), gl);
  cr_ry_r<0, 2>(wr, ld2(Gb + 40), gl);
  cr_ry_r<2, 3>(wr, ld2(Gb + 48), gl);
  v2f w[32];
  u3_lift<3>(w, wr, Gb + 64);        // U3(1), real input
  tail_common<1>(w, Gb, res);
}

__device__ __forceinline__ void run_rz(const float* __restrict__ xb0,
                                       const float* __restrict__ xb1,
                                       const float* __restrict__ Gb, int gl,
                                       v2f res[2]) {
  const bool l0 = gl & 1, l1 = (gl >> 1) & 1, l2 = (gl >> 2) & 1, l3 = (gl >> 3) & 1;
  // shared phase coefficients (element-independent)
  const float t0 = Gb[2], h0 = Gb[3];
  const float t1 = Gb[10], h1 = Gb[11];
  const float t2 = Gb[18], h2 = Gb[19];
  const float t3 = Gb[26], h3 = Gb[27];
  const float h4 = Gb[35], h5 = Gb[43], h6 = Gb[51];
  const float kk0 = (l1 ? t1 : 0.f) + (l2 ? h5 : -h5);
  const float kk1 = (l3 ? t3 : 0.f);
  const float kk2 = (l2 ? t2 : 0.f) + (l3 ? h6 : -h6);
  const float kk3 = (l0 ? t0 : 0.f) + (l1 ? h4 : -h4);
  const float aa = -((l0 ? h0 : 0.f) + (l1 ? h1 : 0.f) + (l2 ? h2 : 0.f) + (l3 ? h3 : 0.f));
  // per-element real envelopes
  float v01[2][4], v23[2][4];
#pragma unroll
  for (int e = 0; e < 2; ++e) {
    float sn[8], cn[8];
    load_sincos(e ? xb1 : xb0, sn, cn);
    const float u0 = l0 ? sn[0] : cn[0];
    const float u2 = l1 ? sn[2] : cn[2];
    const float u4 = l2 ? sn[4] : cn[4];
    const float u6 = l3 ? sn[6] : cn[6];
    const float P = (u0 * u2) * (u4 * u6);
    v01[e][0] = P * (cn[3] * cn[7]); v01[e][1] = P * (sn[3] * cn[7]);
    v01[e][2] = P * (cn[3] * sn[7]); v01[e][3] = P * (sn[3] * sn[7]);
    v23[e][0] = cn[5] * cn[1]; v23[e][1] = sn[5] * cn[1];
    v23[e][2] = cn[5] * sn[1]; v23[e][3] = sn[5] * sn[1];
  }
  v2f w[32];
#pragma unroll
  for (int s = 0; s < 16; ++s) {
    float phv = aa;
    if (s & 1) phv += kk0;
    if (s & 2) phv += kk1;
    if (s & 4) phv += kk2;
    if (s & 8) phv += kk3;
    float sp, cp;
    __sincosf(phv, &sp, &cp);  // shared by both elements
    const float e0 = v01[0][s & 3] * v23[0][s >> 2];
    const float e1 = v01[1][s & 3] * v23[1][s >> 2];
    w[s] = mk2(e0 * cp, e0 * sp);
    w[16 + s] = mk2(e1 * cp, e1 * sp);
  }
  u3_apply<3>(w, Gb + 64);           // U3(1)
  tail_common<2>(w, Gb, res);
}

// ============================ prep ==========================================
struct c2 { float r, i; };
__device__ __forceinline__ c2 cmulh(c2 a, c2 b) { return {a.r * b.r - a.i * b.i, a.r * b.i + a.i * b.r}; }
__device__ __forceinline__ c2 cmulc(c2 a, c2 b) { return {a.r * b.r + a.i * b.i, a.i * b.r - a.r * b.i}; }
__device__ __forceinline__ c2 caddh(c2 a, c2 b) { return {a.r + b.r, a.i + b.i}; }
__device__ void mat2mul(const c2 A[4], const c2 B[4], c2 C[4]) {
  C[0] = caddh(cmulh(A[0], B[0]), cmulh(A[1], B[2]));
  C[1] = caddh(cmulh(A[0], B[1]), cmulh(A[1], B[3]));
  C[2] = caddh(cmulh(A[2], B[0]), cmulh(A[3], B[2]));
  C[3] = caddh(cmulh(A[2], B[1]), cmulh(A[3], B[3]));
}
__device__ void u3m(const float* p, c2 M[4]) {
  float st, ct, sp, cp, sl, cl;
  sincosf(0.5f * p[0], &st, &ct);
  sincosf(p[1], &sp, &cp);
  sincosf(p[2], &sl, &cl);
  M[0] = {ct, 0.f};
  M[1] = {-cl * st, -sl * st};
  M[2] = {cp * st, sp * st};
  M[3] = {(cp * cl - sp * sl) * ct, (sp * cl + cp * sl) * ct};
}
__device__ void rmat(int kind, float th, c2 R[4]) {
  float s, c;
  sincosf(0.5f * th, &s, &c);
  if (kind == 0) { R[0] = {c, 0.f}; R[1] = {0.f, -s}; R[2] = {0.f, -s}; R[3] = {c, 0.f}; }
  else if (kind == 1) { R[0] = {c, 0.f}; R[1] = {-s, 0.f}; R[2] = {s, 0.f}; R[3] = {c, 0.f}; }
  else { R[0] = {c, -s}; R[1] = {0.f, 0.f}; R[2] = {0.f, 0.f}; R[3] = {c, s}; }
}
__device__ void storeM(float* dst, const c2 M[4]) {
#pragma unroll
  for (int j = 0; j < 4; ++j) { dst[2 * j] = M[j].r; dst[2 * j + 1] = M[j].i; }
}

__global__ void qcnn_prep(const float* __restrict__ crx, const float* __restrict__ u3x,
                          const float* __restrict__ cry, const float* __restrict__ u3y,
                          const float* __restrict__ crz, const float* __restrict__ u3z,
                          float* __restrict__ G) {
  const int br = threadIdx.x;
  if (br >= 3) return;
  const float* crp = (br == 0) ? crx : (br == 1) ? cry : crz;
  const float* u3p = (br == 0) ? u3x : (br == 1) ? u3y : u3z;
  float* Gb = G + br * 128;

  const int crIdx[8] = {0, 1, 2, 3, 4, 5, 6, 9};
#pragma unroll
  for (int i = 0; i < 8; ++i) {
    const float th = crp[crIdx[i]];
    float s, c;
    sincosf(0.5f * th, &s, &c);
    Gb[i * 8] = c;
    Gb[i * 8 + 1] = s;
    Gb[i * 8 + 2] = th;
    Gb[i * 8 + 3] = 0.5f * th;
  }
  c2 U1v[4], U3v[4], U5v[4], U7a[4], U7b[4], U3f[4], R[4], T[4], T2[4];
  u3m(u3p + 0, U1v);
  u3m(u3p + 3, U3v);
  u3m(u3p + 6, U5v);
  u3m(u3p + 9, U7a);
  u3m(u3p + 12, U3f);
  u3m(u3p + 15, U7b);
  storeM(Gb + 64, U1v);
  storeM(Gb + 72, U3v);
  rmat(br, crp[7], R);
  mat2mul(R, U3v, T);
  storeM(Gb + 80, T);
  storeM(Gb + 88, U5v);
  mat2mul(U7b, U7a, T);
  storeM(Gb + 96, T);
  rmat(br, crp[8], R);
  mat2mul(R, U7a, T);
  mat2mul(U7b, T, T2);
  storeM(Gb + 104, T2);
  const float n00 = U3f[0].r * U3f[0].r + U3f[0].i * U3f[0].i;
  const float n01 = U3f[1].r * U3f[1].r + U3f[1].i * U3f[1].i;
  const float n10 = U3f[2].r * U3f[2].r + U3f[2].i * U3f[2].i;
  const float n11 = U3f[3].r * U3f[3].r + U3f[3].i * U3f[3].i;
  const c2 g01 = cmulc(U3f[0], U3f[1]);
  const c2 g23 = cmulc(U3f[2], U3f[3]);
  Gb[112] = n00 - n10;
  Gb[113] = n01 - n11;
  Gb[114] = 2.f * (g01.r - g23.r);
  Gb[115] = 2.f * (g01.i - g23.i);
}

// ============================ main ==========================================
__global__ __launch_bounds__(256) void qcnn_main(
    const float* __restrict__ x, const float* __restrict__ G,
    const float* __restrict__ w1, const float* __restrict__ b1,
    const float* __restrict__ w2, const float* __restrict__ b2,
    float* __restrict__ out, int B) {
  const int gid = blockIdx.x * blockDim.x + threadIdx.x;
  const int grp = gid >> 4;  // 16-lane group, 2 interleaved elements
  const int gl = threadIdx.x & 15;
  const int b0 = grp * 2;
  if (b0 >= B) return;  // B is even; b0+1 < B whenever b0 < B
  const float* xb0 = x + b0 * 8;
  const float* xb1 = x + (b0 + 1) * 8;

  v2f fx[2], fy[2], fz[2];
  run_rx(xb0, xb1, G, gl, fx);
  run_ry(xb0, xb1, G + 128, gl, fy);
  run_rz(xb0, xb1, G + 256, gl, fz);

  // MLP head, lane-parallel over 12 hidden units; weights shared by both elems
  const int j = (gl < 12) ? gl : 0;
  const float* w1r = w1 + j * 6;
  const float w10 = w1r[0], w11 = w1r[1], w12 = w1r[2];
  const float w13 = w1r[3], w14 = w1r[4], w15 = w1r[5];
  const float b1v = b1[j], w2v = w2[j], b2v = b2[0];
  float a0 = b1v + w10 * fx[0].x + w11 * fx[0].y + w12 * fy[0].x +
             w13 * fy[0].y + w14 * fz[0].x + w15 * fz[0].y;
  float a1 = b1v + w10 * fx[1].x + w11 * fx[1].y + w12 * fy[1].x +
             w13 * fy[1].y + w14 * fz[1].x + w15 * fz[1].y;
  const float e0 = __expf(2.f * a0), e1 = __expf(2.f * a1);
  const float th0 = 1.f - 2.f * __builtin_amdgcn_rcpf(e0 + 1.f);
  const float th1 = 1.f - 2.f * __builtin_amdgcn_rcpf(e1 + 1.f);
  float t0 = (gl < 12) ? w2v * th0 : 0.f;
  float t1 = (gl < 12) ? w2v * th1 : 0.f;
  t0 += swz1<1>(t0); t1 += swz1<1>(t1);
  t0 += swz1<2>(t0); t1 += swz1<2>(t1);
  t0 += swz1<4>(t0); t1 += swz1<4>(t1);
  t0 += swz1<8>(t0); t1 += swz1<8>(t1);
  const float r0 = __builtin_amdgcn_rcpf(1.f + __expf(-(t0 + b2v)));
  const float r1 = __builtin_amdgcn_rcpf(1.f + __expf(-(t1 + b2v)));
  if (gl == 0) {
    out[b0] = r0;
    out[b0 + 1] = r1;
  }
}

extern "C" void kernel_launch(void* const* d_in, const int* in_sizes, int n_in,
                              void* d_out, int out_size, void* d_ws,
                              size_t ws_size, hipStream_t stream) {
  const float* x = (const float*)d_in[0];
  const float* crx = (const float*)d_in[1];
  const float* u3x = (const float*)d_in[2];
  const float* cry = (const float*)d_in[3];
  const float* u3y = (const float*)d_in[4];
  const float* crz = (const float*)d_in[5];
  const float* u3z = (const float*)d_in[6];
  const float* w1 = (const float*)d_in[7];
  const float* b1 = (const float*)d_in[8];
  const float* w2 = (const float*)d_in[9];
  const float* b2 = (const float*)d_in[10];
  float* out = (float*)d_out;
  float* G = (float*)d_ws;  // 384 floats
  const int B = in_sizes[0] / 8;

  hipLaunchKernelGGL(qcnn_prep, dim3(1), dim3(64), 0, stream, crx, u3x, cry,
                     u3y, crz, u3z, G);
  const int ngroups = (B + 1) / 2;  // 2 elements per 16-lane group
  const int threads = 256;
  const int blocks = (ngroups * 16 + threads - 1) / threads;
  hipLaunchKernelGGL(qcnn_main, dim3(blocks), dim3(threads), 0, stream, x, G,
                     w1, b1, w2, b2, out, B);
}